// Round 10
// baseline (105.040 us; speedup 1.0000x reference)
//
#include <hip/hip_runtime.h>

typedef __attribute__((ext_vector_type(8))) short bf16x8;
typedef __attribute__((ext_vector_type(4))) float f32x4;
typedef __attribute__((ext_vector_type(4))) unsigned int u32x4;

#define NB 64
#define SQ 198
#define SKV 206
#define DM 768
#define NH 12
#define NROWS (NB * SKV)   // 13184
#define NCOL 2304          // Q | K | V columns

static __device__ __forceinline__ unsigned short f2b(float f) {
  union { float f; unsigned u; } v; v.f = f;
  unsigned r = v.u + 0x7FFFu + ((v.u >> 16) & 1u);
  return (unsigned short)(r >> 16);
}

typedef const __attribute__((address_space(1))) unsigned int g_u32;
typedef __attribute__((address_space(3))) unsigned int l_u32;
static __device__ __forceinline__ void gload_lds16(const void* g, void* l) {
  __builtin_amdgcn_global_load_lds((g_u32*)g, (l_u32*)l, 16, 0, 0);
}

// ---------- transpose W -> bf16 Wt[w][n][k] ----------
__global__ __launch_bounds__(256) void k_conv_w(const float* __restrict__ Wq,
                                                const float* __restrict__ Wk,
                                                const float* __restrict__ Wv,
                                                unsigned short* __restrict__ wt) {
  __shared__ float L[64][65];
  int w = blockIdx.z;
  int n0 = blockIdx.x * 64, k0 = blockIdx.y * 64;
  const float* W = (w == 0) ? Wq : (w == 1) ? Wk : Wv;
  int tid = threadIdx.x;
#pragma unroll
  for (int i = 0; i < 16; ++i) {
    int idx = i * 256 + tid;
    int lr = idx >> 6, lc = idx & 63;
    L[lr][lc] = W[(k0 + lr) * DM + n0 + lc];
  }
  __syncthreads();
  unsigned short* dst = wt + w * DM * DM;
#pragma unroll
  for (int o = 0; o < 2; ++o) {
    int gi = o * 256 + tid;
    int rn = gi >> 3, g = gi & 7;
    unsigned wrd[4];
#pragma unroll
    for (int jj = 0; jj < 4; ++jj) {
      float f0 = L[g * 8 + jj * 2 + 0][rn];
      float f1 = L[g * 8 + jj * 2 + 1][rn];
      wrd[jj] = f2b(f0) | ((unsigned)f2b(f1) << 16);
    }
    u32x4 o4 = {wrd[0], wrd[1], wrd[2], wrd[3]};
    *(u32x4*)(dst + (n0 + rn) * DM + k0 + g * 8) = o4;
  }
}

// ---------- fused convert+QKV GEMM: 128x256, BK=32, 3-buf, A reg-staged f32->bf16 ----------
// A: per thread 2x global_load_dwordx4 (f32) -> 4x v_cvt_pk_bf16_f32 -> swizzled
// ds_write_b128 (phys granule = pg ^ ((row>>1)&3), matches read swizzle, R7-verified).
// B: global_load_lds from pre-swizzled bf16 Wt source (unchanged from R8).
// vmcnt per tile: 4 loads issued (2 f32-A + 2 B). Write A(t+1): vmcnt(6) [+compiler
// reg-dep wait]; open buf t+1: vmcnt(4) leaves exactly tile-t's 4 in flight.
__global__ __launch_bounds__(512, 4) void k_gemm(const float* __restrict__ hid,
                                                 const float* __restrict__ mem,
                                                 const unsigned short* __restrict__ wt,
                                                 const float* __restrict__ bq,
                                                 const float* __restrict__ bk,
                                                 const float* __restrict__ bv,
                                                 unsigned short* __restrict__ cout) {
  __shared__ __align__(16) unsigned char smem[73728];
  // bijective XCD swizzle (nwg=927: q=115, r=7)
  int o = blockIdx.x, xcd = o & 7, rest = o >> 3;
  int sid = (xcd < 7 ? xcd * 116 : 812 + (xcd - 7) * 115) + rest;
  int mtile = sid / 9, ntile = sid - mtile * 9;
  int row0 = mtile * 128, col0 = ntile * 256;
  int w = ntile / 3;
  int colw0 = (ntile - w * 3) * 256;
  int tid = threadIdx.x, lane = tid & 63, wid = tid >> 6;
  int wm = wid >> 2, wn = wid & 3;      // 2M x 4N waves, each 64x64 out
  int l = lane & 15, gq = lane >> 4;
  const unsigned short* wbase = wt + w * DM * DM;

  // per-thread staging geometry: row sr = tid>>2, granule pg = tid&3 (8 elems)
  int sr = tid >> 2, pg = tid & 3;
  // A source: f32 from hid/mem (fused convert)
  const float* aF;
  {
    int arow = row0 + sr;
    int ab = arow / SKV, as = arow - ab * SKV;
    aF = (as < SQ ? hid + (size_t)(ab * SQ + as) * DM
                  : mem + (size_t)(as - SQ) * DM) + pg * 8;
  }
  // A LDS write offset (within buf): swizzled
  int aWr = sr * 64 + ((pg ^ ((sr >> 1) & 3)) << 4);
  // B source: pre-swizzled bf16 (linear gload_lds dest)
  const unsigned short* bP0;
  const unsigned short* bP1;
  {
    int sg = pg ^ ((sr >> 1) & 3);
    bP0 = wbase + (colw0 + sr) * DM + sg * 8;
    bP1 = wbase + (colw0 + 128 + sr) * DM + sg * 8;
  }
  int ldsW = wid * 1024;                // wave-uniform LDS base for gload (HW adds lane*16)

  f32x4 zero = {0.f, 0.f, 0.f, 0.f};
  f32x4 acc[4][4];
#pragma unroll
  for (int i = 0; i < 4; ++i)
#pragma unroll
    for (int j = 0; j < 4; ++j) acc[i][j] = zero;

  // prologue: issue gA(0), gA(1), B(0), B(1); full drain once; write A(0)
  float4 h0a = ((const float4*)(aF + 0))[0];
  float4 h0b = ((const float4*)(aF + 0))[1];
  float4 hda = ((const float4*)(aF + 32))[0];
  float4 hdb = ((const float4*)(aF + 32))[1];
  gload_lds16(bP0 + 0, smem + 8192 + ldsW);
  gload_lds16(bP1 + 0, smem + 16384 + ldsW);
  gload_lds16(bP0 + 32, smem + 24576 + 8192 + ldsW);
  gload_lds16(bP1 + 32, smem + 24576 + 16384 + ldsW);
  asm volatile("s_waitcnt vmcnt(0)" ::: "memory");
  {
    unsigned c0, c1, c2, c3;
    asm("v_cvt_pk_bf16_f32 %0, %1, %2" : "=v"(c0) : "v"(h0a.x), "v"(h0a.y));
    asm("v_cvt_pk_bf16_f32 %0, %1, %2" : "=v"(c1) : "v"(h0a.z), "v"(h0a.w));
    asm("v_cvt_pk_bf16_f32 %0, %1, %2" : "=v"(c2) : "v"(h0b.x), "v"(h0b.y));
    asm("v_cvt_pk_bf16_f32 %0, %1, %2" : "=v"(c3) : "v"(h0b.z), "v"(h0b.w));
    u32x4 wv = {c0, c1, c2, c3};
    *(u32x4*)(smem + aWr) = wv;
  }
  asm volatile("s_waitcnt lgkmcnt(0)" ::: "memory");
  __builtin_amdgcn_s_barrier();

  int swx = (gq * 16) ^ (((l >> 1) & 3) << 4);
  int aRd = (wm * 64 + l) * 64 + swx;            // + mi*1024 + buf off
  int bRd = 8192 + (wn * 64 + l) * 64 + swx;     // + ni*1024 + buf off

  int q = 0;          // t % 3
  int qn = 2;         // (t+2) % 3
  int qw = 1;         // (t+1) % 3
#pragma unroll 1
  for (int t = 0; t < 24; ++t) {
    const unsigned char* bp = smem + q * 24576;
    // a: issue tile t+2 loads (2 f32-A to regs, 2 B gload_lds)
    float4 na, nb2;
    if (t < 22) {
      const float4* pA = (const float4*)(aF + (t + 2) * 32);
      na = pA[0]; nb2 = pA[1];
      unsigned char* ip = smem + qn * 24576;
      int kI = (t + 2) * 32;
      gload_lds16(bP0 + kI, ip + 8192 + ldsW);
      gload_lds16(bP1 + kI, ip + 16384 + ldsW);
    }
    // b: convert + ds_write A(t+1) (hold regs from last tile)
    if (t < 23) {
      if (t < 22)       { asm volatile("s_waitcnt vmcnt(6)" ::: "memory"); }
      else              { asm volatile("s_waitcnt vmcnt(2)" ::: "memory"); }
      unsigned c0, c1, c2, c3;
      asm("v_cvt_pk_bf16_f32 %0, %1, %2" : "=v"(c0) : "v"(hda.x), "v"(hda.y));
      asm("v_cvt_pk_bf16_f32 %0, %1, %2" : "=v"(c1) : "v"(hda.z), "v"(hda.w));
      asm("v_cvt_pk_bf16_f32 %0, %1, %2" : "=v"(c2) : "v"(hdb.x), "v"(hdb.y));
      asm("v_cvt_pk_bf16_f32 %0, %1, %2" : "=v"(c3) : "v"(hdb.z), "v"(hdb.w));
      u32x4 wv = {c0, c1, c2, c3};
      *(u32x4*)(smem + qw * 24576 + aWr) = wv;
      hda = na; hdb = nb2;
    }
    // c/d: read frags of tile t and MFMA
    bf16x8 a[4], b[4];
#pragma unroll
    for (int mi = 0; mi < 4; ++mi) a[mi] = *(const bf16x8*)(bp + aRd + mi * 1024);
#pragma unroll
    for (int ni = 0; ni < 4; ++ni) b[ni] = *(const bf16x8*)(bp + bRd + ni * 1024);
    __builtin_amdgcn_s_setprio(1);
#pragma unroll
    for (int mi = 0; mi < 4; ++mi)
#pragma unroll
      for (int ni = 0; ni < 4; ++ni)
        acc[mi][ni] = __builtin_amdgcn_mfma_f32_16x16x32_bf16(a[mi], b[ni], acc[mi][ni], 0, 0, 0);
    __builtin_amdgcn_s_setprio(0);
    // e: open buffer t+1 (B(t+1) landed; A(t+1) ds_write drained) ; f: barrier
    if (t < 22)       { asm volatile("s_waitcnt vmcnt(4)" ::: "memory"); }
    else if (t == 22) { asm volatile("s_waitcnt vmcnt(0)" ::: "memory"); }
    asm volatile("s_waitcnt lgkmcnt(0)" ::: "memory");
    __builtin_amdgcn_s_barrier();
    q = (q == 2) ? 0 : q + 1;
    qn = (qn == 2) ? 0 : qn + 1;
    qw = (qw == 2) ? 0 : qw + 1;
  }

  // epilogue: bias + bf16 C through LDS (128 rows x 512B, (row&7)<<4 XOR)
  const float* bias = (w == 0) ? bq : (w == 1) ? bk : bv;
  float bb[4];
#pragma unroll
  for (int ni = 0; ni < 4; ++ni) bb[ni] = bias[colw0 + wn * 64 + ni * 16 + l];

  __syncthreads();
#pragma unroll
  for (int mi = 0; mi < 4; ++mi)
#pragma unroll
    for (int ni = 0; ni < 4; ++ni)
#pragma unroll
      for (int rr = 0; rr < 4; ++rr) {
        int row = wm * 64 + mi * 16 + gq * 4 + rr;
        int col = wn * 64 + ni * 16 + l;
        *(unsigned short*)(smem + row * 512 + ((col * 2) ^ ((row & 7) << 4))) =
            f2b(acc[mi][ni][rr] + bb[ni]);
      }
  __syncthreads();
#pragma unroll
  for (int it = 0; it < 8; ++it) {
    int gi = it * 512 + tid;
    int row = gi >> 5, gran = gi & 31;
    u32x4 v = *(const u32x4*)(smem + row * 512 + ((gran * 16) ^ ((row & 7) << 4)));
    *(u32x4*)(cout + (row0 + row) * NCOL + col0 + gran * 8) = v;
  }
}

// ---------- attention (unchanged): swapped QK^T, in-register P, 52KB LDS ----------
static __device__ __forceinline__ int vt_off(int row, int col) {
  return row * 416 + ((col * 2) ^ (((row >> 3) & 1) << 4));
}

__global__ __launch_bounds__(256, 3) void k_attn(const unsigned short* __restrict__ cqkv,
                                                 float* __restrict__ out) {
  __shared__ __align__(16) unsigned short Ksh[208 * 64];
  __shared__ __align__(16) unsigned char  VtB[64 * 416];
  int bh = blockIdx.x;
  int b = bh / NH, h = bh - b * NH;
  int tid = threadIdx.x, lane = tid & 63, wid = tid >> 6;
  int g = lane >> 4, l = lane & 15;
  const unsigned short* Cb = cqkv + (b * SKV) * NCOL + h * 64;

  if (tid < 64) *(unsigned*)(VtB + vt_off(tid, 206)) = 0u;
  for (int i = tid; i < 208 * 8; i += 256) {
    int row = i >> 3, gg = i & 7;
    int srow = (row < SKV) ? row : (SKV - 1);
    u32x4 v = *(const u32x4*)(Cb + srow * NCOL + 768 + gg * 8);
    *(u32x4*)((unsigned char*)Ksh + ((row * 128 + gg * 16) ^ ((row & 7) << 4))) = v;
  }
  for (int i = tid; i < 206 * 8; i += 256) {
    int key = i >> 3, gg = i & 7;
    u32x4 v = *(const u32x4*)(Cb + key * NCOL + 1536 + gg * 8);
    union { u32x4 v4; unsigned short e[8]; } u; u.v4 = v;
#pragma unroll
    for (int j = 0; j < 8; ++j)
      *(unsigned short*)(VtB + vt_off(gg * 8 + j, key)) = u.e[j];
  }
  __syncthreads();

  const float scale = 0.125f;
  f32x4 zero4 = {0.f, 0.f, 0.f, 0.f};
  int srcA = ((g & 1) << 5) + l;
  int srcB = srcA + 16;
  bool hiHalf = (g >= 2);

  for (int qt = wid; qt < 13; qt += 4) {
    int qr = qt * 16 + l;
    int qld = qr > 197 ? 197 : qr;
    const unsigned short* qp = Cb + qld * NCOL + g * 8;
    bf16x8 qa0 = *(const bf16x8*)qp;
    bf16x8 qa1 = *(const bf16x8*)(qp + 32);

    f32x4 sc[13];
#pragma unroll
    for (int nt = 0; nt < 13; ++nt) sc[nt] = zero4;
#pragma unroll
    for (int nt = 0; nt < 13; ++nt) {
      int key = nt * 16 + l;
      int rb = key * 128, sw = (key & 7) << 4, kb = g * 16;
      bf16x8 kb0 = *(const bf16x8*)((const unsigned char*)Ksh + rb + (kb ^ sw));
      bf16x8 kb1 = *(const bf16x8*)((const unsigned char*)Ksh + rb + ((kb + 64) ^ sw));
      sc[nt] = __builtin_amdgcn_mfma_f32_16x16x32_bf16(kb0, qa0, sc[nt], 0, 0, 0);
      sc[nt] = __builtin_amdgcn_mfma_f32_16x16x32_bf16(kb1, qa1, sc[nt], 0, 0, 0);
    }

    float mx = -1e30f;
#pragma unroll
    for (int nt = 0; nt < 13; ++nt)
#pragma unroll
      for (int r = 0; r < 4; ++r) {
        int key = nt * 16 + g * 4 + r;
        float s = sc[nt][r] * scale;
        bool ok = (key < 197 || qr == 197) && (key < SKV);
        s = ok ? s : -1e30f;
        sc[nt][r] = s;
        mx = fmaxf(mx, s);
      }
    mx = fmaxf(mx, __shfl_xor(mx, 16));
    mx = fmaxf(mx, __shfl_xor(mx, 32));
    float sum = 0.f;
#pragma unroll
    for (int nt = 0; nt < 13; ++nt)
#pragma unroll
      for (int r = 0; r < 4; ++r) {
        float p = __expf(sc[nt][r] - mx);
        sc[nt][r] = p;
        sum += p;
      }
    sum += __shfl_xor(sum, 16);
    sum += __shfl_xor(sum, 32);
    float inv = 1.0f / sum;

    unsigned pk0[13], pk1[13];
#pragma unroll
    for (int nt = 0; nt < 13; ++nt) {
      asm("v_cvt_pk_bf16_f32 %0, %1, %2" : "=v"(pk0[nt]) : "v"(sc[nt][0]), "v"(sc[nt][1]));
      asm("v_cvt_pk_bf16_f32 %0, %1, %2" : "=v"(pk1[nt]) : "v"(sc[nt][2]), "v"(sc[nt][3]));
    }

    f32x4 ctx[4];
#pragma unroll
    for (int dt = 0; dt < 4; ++dt) ctx[dt] = zero4;
#pragma unroll
    for (int c = 0; c < 7; ++c) {
      union { unsigned w[4]; bf16x8 v; } pa;
      if (c < 6) {
        int n0 = 2 * c, n1 = 2 * c + 1;
        unsigned a0 = (unsigned)__shfl((int)pk0[n0], srcA), b0 = (unsigned)__shfl((int)pk0[n1], srcA);
        unsigned a1 = (unsigned)__shfl((int)pk1[n0], srcA), b1 = (unsigned)__shfl((int)pk1[n1], srcA);
        unsigned a2 = (unsigned)__shfl((int)pk0[n0], srcB), b2 = (unsigned)__shfl((int)pk0[n1], srcB);
        unsigned a3 = (unsigned)__shfl((int)pk1[n0], srcB), b3 = (unsigned)__shfl((int)pk1[n1], srcB);
        pa.w[0] = hiHalf ? b0 : a0;
        pa.w[1] = hiHalf ? b1 : a1;
        pa.w[2] = hiHalf ? b2 : a2;
        pa.w[3] = hiHalf ? b3 : a3;
      } else {
        unsigned a0 = (unsigned)__shfl((int)pk0[12], srcA);
        unsigned a1 = (unsigned)__shfl((int)pk1[12], srcA);
        unsigned a2 = (unsigned)__shfl((int)pk0[12], srcB);
        unsigned a3 = (unsigned)__shfl((int)pk1[12], srcB);
        pa.w[0] = hiHalf ? 0u : a0;
        pa.w[1] = hiHalf ? 0u : a1;
        pa.w[2] = hiHalf ? 0u : a2;
        pa.w[3] = hiHalf ? 0u : a3;
      }
      int colb = c * 32 + g * 8;
      if (c == 6 && hiHalf) colb = 0;
#pragma unroll
      for (int dt = 0; dt < 4; ++dt) {
        bf16x8 vb = *(const bf16x8*)(VtB + vt_off(dt * 16 + l, colb));
        ctx[dt] = __builtin_amdgcn_mfma_f32_16x16x32_bf16(pa.v, vb, ctx[dt], 0, 0, 0);
      }
    }

    float invr[4];
#pragma unroll
    for (int r = 0; r < 4; ++r) invr[r] = __shfl(inv, g * 4 + r);
#pragma unroll
    for (int dt = 0; dt < 4; ++dt)
#pragma unroll
      for (int r = 0; r < 4; ++r) {
        int qo = qt * 16 + g * 4 + r;
        if (qo < SQ)
          out[(b * SQ + qo) * DM + h * 64 + dt * 16 + l] = ctx[dt][r] * invr[r];
      }
  }
}

extern "C" void kernel_launch(void* const* d_in, const int* in_sizes, int n_in,
                              void* d_out, int out_size, void* d_ws, size_t ws_size,
                              hipStream_t stream) {
  const float* hid = (const float*)d_in[0];
  const float* mem = (const float*)d_in[1];
  const float* Wq  = (const float*)d_in[2];
  const float* bq  = (const float*)d_in[3];
  const float* Wk  = (const float*)d_in[4];
  const float* bk  = (const float*)d_in[5];
  const float* Wv  = (const float*)d_in[6];
  const float* bv  = (const float*)d_in[7];
  float* out = (float*)d_out;

  unsigned short* wtb  = (unsigned short*)d_ws;           // 3*768*768 bf16
  unsigned short* cbuf = wtb + 3 * DM * DM;               // 13184*2304 bf16

  k_conv_w<<<dim3(12, 12, 3), 256, 0, stream>>>(Wq, Wk, Wv, wtb);
  k_gemm<<<dim3(927), 512, 0, stream>>>(hid, mem, wtb, bq, bk, bv, cbuf);
  k_attn<<<dim3(NB * NH), 256, 0, stream>>>(cbuf, out);
}

// Round 11
// 101.377 us; speedup vs baseline: 1.0361x; 1.0361x over previous
//
#include <hip/hip_runtime.h>

typedef __attribute__((ext_vector_type(8))) short bf16x8;
typedef __attribute__((ext_vector_type(4))) float f32x4;
typedef __attribute__((ext_vector_type(4))) unsigned int u32x4;

#define NB 64
#define SQ 198
#define SKV 206
#define DM 768
#define NH 12
#define NROWS (NB * SKV)   // 13184
#define NCOL 2304          // Q | K | V columns
#define NCONVX 4944        // conv_x blocks: 13184*768/8/256

static __device__ __forceinline__ unsigned short f2b(float f) {
  union { float f; unsigned u; } v; v.f = f;
  unsigned r = v.u + 0x7FFFu + ((v.u >> 16) & 1u);
  return (unsigned short)(r >> 16);
}

typedef const __attribute__((address_space(1))) unsigned int g_u32;
typedef __attribute__((address_space(3))) unsigned int l_u32;
static __device__ __forceinline__ void gload_lds16(const void* g, void* l) {
  __builtin_amdgcn_global_load_lds((g_u32*)g, (l_u32*)l, 16, 0, 0);
}

// ---------- merged converts: blocks [0,4944) build Xkv; [4944,5376) transpose W ----------
__global__ __launch_bounds__(256) void k_conv(const float* __restrict__ hid,
                                              const float* __restrict__ mem,
                                              const float* __restrict__ Wq,
                                              const float* __restrict__ Wk,
                                              const float* __restrict__ Wv,
                                              unsigned short* __restrict__ xkv,
                                              unsigned short* __restrict__ wt) {
  __shared__ float L[64][65];
  int bid = blockIdx.x, tid = threadIdx.x;
  if (bid < NCONVX) {
    // Xkv[13184][768]: rows = hidden(198) + broadcast memory(8) per batch
    int idx = (bid * 256 + tid) * 8;
    int r = idx / DM;
    int c = idx - r * DM;
    int b = r / SKV, s = r - b * SKV;
    const float* src = (s < SQ) ? (hid + (b * SQ + s) * DM + c)
                                : (mem + (s - SQ) * DM + c);
    float4 v0 = ((const float4*)src)[0];
    float4 v1 = ((const float4*)src)[1];
    unsigned w0 = f2b(v0.x) | ((unsigned)f2b(v0.y) << 16);
    unsigned w1 = f2b(v0.z) | ((unsigned)f2b(v0.w) << 16);
    unsigned w2 = f2b(v1.x) | ((unsigned)f2b(v1.y) << 16);
    unsigned w3 = f2b(v1.z) | ((unsigned)f2b(v1.w) << 16);
    u32x4 o = {w0, w1, w2, w3};
    *(u32x4*)(xkv + idx) = o;
    return;
  }
  // W transpose: wt[w][n][k] bf16
  int r = bid - NCONVX;                 // 432 = 12 x 12 x 3
  int nx = r % 12, ky = (r / 12) % 12, w = r / 144;
  int n0 = nx * 64, k0 = ky * 64;
  const float* W = (w == 0) ? Wq : (w == 1) ? Wk : Wv;
#pragma unroll
  for (int i = 0; i < 16; ++i) {
    int idx = i * 256 + tid;
    int lr = idx >> 6, lc = idx & 63;
    L[lr][lc] = W[(k0 + lr) * DM + n0 + lc];
  }
  __syncthreads();
  unsigned short* dst = wt + w * DM * DM;
#pragma unroll
  for (int o = 0; o < 2; ++o) {
    int gi = o * 256 + tid;
    int rn = gi >> 3, g = gi & 7;
    unsigned wrd[4];
#pragma unroll
    for (int jj = 0; jj < 4; ++jj) {
      float f0 = L[g * 8 + jj * 2 + 0][rn];
      float f1 = L[g * 8 + jj * 2 + 1][rn];
      wrd[jj] = f2b(f0) | ((unsigned)f2b(f1) << 16);
    }
    u32x4 o4 = {wrd[0], wrd[1], wrd[2], wrd[3]};
    *(u32x4*)(dst + (n0 + rn) * DM + k0 + g * 8) = o4;
  }
}

// ---------- fused QKV GEMM (R8 exact): 128x256 tile, BK=32, 3-buf, 2 blocks/CU ----------
// Per-wave 64x64 (acc[4][4] = 64 VGPR) -> 4 waves/SIMD. LDS 3 x 24KB: A[0,8K) B[8K,24K).
// Granule swizzle phys = g ^ ((row>>1)&3) (zero-conflict). One barrier per K-tile;
// counted vmcnt(3): buffer-open vmcnt ALWAYS immediately precedes s_barrier.
__global__ __launch_bounds__(512, 4) void k_gemm(const unsigned short* __restrict__ xkv,
                                                 const unsigned short* __restrict__ wt,
                                                 const float* __restrict__ bq,
                                                 const float* __restrict__ bk,
                                                 const float* __restrict__ bv,
                                                 unsigned short* __restrict__ cout) {
  __shared__ __align__(16) unsigned char smem[73728];
  // bijective XCD swizzle (nwg=927: q=115, r=7)
  int o = blockIdx.x, xcd = o & 7, rest = o >> 3;
  int sid = (xcd < 7 ? xcd * 116 : 812 + (xcd - 7) * 115) + rest;
  int mtile = sid / 9, ntile = sid - mtile * 9;
  int row0 = mtile * 128, col0 = ntile * 256;
  int w = ntile / 3;
  int colw0 = (ntile - w * 3) * 256;
  int tid = threadIdx.x, lane = tid & 63, wid = tid >> 6;
  int wm = wid >> 2, wn = wid & 3;      // 2M x 4N waves, each 64x64 out
  int l = lane & 15, gq = lane >> 4;
  const unsigned short* wbase = wt + w * DM * DM;

  const unsigned short* aP;
  const unsigned short* bP0;
  const unsigned short* bP1;
  {
    int sr = tid >> 2, pg = tid & 3, sg = pg ^ ((sr >> 1) & 3);
    aP  = xkv   + (row0 + sr) * DM + sg * 8;            // M = 103*128 exact
    bP0 = wbase + (colw0 + sr) * DM + sg * 8;
    bP1 = wbase + (colw0 + 128 + sr) * DM + sg * 8;
  }
  int ldsW = wid * 1024;                // wave-uniform LDS base (HW adds lane*16)

  f32x4 zero = {0.f, 0.f, 0.f, 0.f};
  f32x4 acc[4][4];
#pragma unroll
  for (int i = 0; i < 4; ++i)
#pragma unroll
    for (int j = 0; j < 4; ++j) acc[i][j] = zero;

  // prologue: stage tiles 0,1 (6 loads/thread)
#pragma unroll
  for (int p = 0; p < 2; ++p) {
    int bo = p * 24576;
    gload_lds16(aP  + p * 32, smem + bo + ldsW);
    gload_lds16(bP0 + p * 32, smem + bo + 8192 + ldsW);
    gload_lds16(bP1 + p * 32, smem + bo + 16384 + ldsW);
  }
  asm volatile("s_waitcnt vmcnt(3)" ::: "memory");   // tile 0 landed (this wave)
  __builtin_amdgcn_s_barrier();                      // ... and for all waves

  int swx = (gq * 16) ^ (((l >> 1) & 3) << 4);
  int aRd = (wm * 64 + l) * 64 + swx;            // + mi*1024 + buf off
  int bRd = 8192 + (wn * 64 + l) * 64 + swx;     // + ni*1024 + buf off

  int q = 0;          // t % 3
  int qn = 2;         // (t+2) % 3
#pragma unroll 1
  for (int t = 0; t < 24; ++t) {
    const unsigned char* bp = smem + q * 24576;
    if (t < 22) {                       // issue stage of tile t+2 first
      unsigned char* ip = smem + qn * 24576;
      int kI = (t + 2) * 32;
      gload_lds16(aP  + kI, ip + ldsW);
      gload_lds16(bP0 + kI, ip + 8192 + ldsW);
      gload_lds16(bP1 + kI, ip + 16384 + ldsW);
    }
    bf16x8 a[4], b[4];
#pragma unroll
    for (int mi = 0; mi < 4; ++mi) a[mi] = *(const bf16x8*)(bp + aRd + mi * 1024);
#pragma unroll
    for (int ni = 0; ni < 4; ++ni) b[ni] = *(const bf16x8*)(bp + bRd + ni * 1024);
    __builtin_amdgcn_s_setprio(1);
#pragma unroll
    for (int mi = 0; mi < 4; ++mi)
#pragma unroll
      for (int ni = 0; ni < 4; ++ni)
        acc[mi][ni] = __builtin_amdgcn_mfma_f32_16x16x32_bf16(a[mi], b[ni], acc[mi][ni], 0, 0, 0);
    __builtin_amdgcn_s_setprio(0);
    if (t < 22)       { asm volatile("s_waitcnt vmcnt(3)" ::: "memory"); }
    else if (t == 22) { asm volatile("s_waitcnt vmcnt(0)" ::: "memory"); }
    __builtin_amdgcn_s_barrier();
    q = (q == 2) ? 0 : q + 1;
    qn = (qn == 2) ? 0 : qn + 1;
  }

  // epilogue: bias + bf16 C through LDS (128 rows x 512B, (row&7)<<4 XOR)
  const float* bias = (w == 0) ? bq : (w == 1) ? bk : bv;
  float bb[4];
#pragma unroll
  for (int ni = 0; ni < 4; ++ni) bb[ni] = bias[colw0 + wn * 64 + ni * 16 + l];

  __syncthreads();
#pragma unroll
  for (int mi = 0; mi < 4; ++mi)
#pragma unroll
    for (int ni = 0; ni < 4; ++ni)
#pragma unroll
      for (int rr = 0; rr < 4; ++rr) {
        int row = wm * 64 + mi * 16 + gq * 4 + rr;
        int col = wn * 64 + ni * 16 + l;
        *(unsigned short*)(smem + row * 512 + ((col * 2) ^ ((row & 7) << 4))) =
            f2b(acc[mi][ni][rr] + bb[ni]);
      }
  __syncthreads();
#pragma unroll
  for (int it = 0; it < 8; ++it) {
    int gi = it * 512 + tid;
    int row = gi >> 5, gran = gi & 31;
    u32x4 v = *(const u32x4*)(smem + row * 512 + ((gran * 16) ^ ((row & 7) << 4)));
    *(u32x4*)(cout + (row0 + row) * NCOL + col0 + gran * 8) = v;
  }
}

// ---------- attention (unchanged): swapped QK^T, in-register P, 52KB LDS ----------
static __device__ __forceinline__ int vt_off(int row, int col) {
  return row * 416 + ((col * 2) ^ (((row >> 3) & 1) << 4));
}

__global__ __launch_bounds__(256, 3) void k_attn(const unsigned short* __restrict__ cqkv,
                                                 float* __restrict__ out) {
  __shared__ __align__(16) unsigned short Ksh[208 * 64];
  __shared__ __align__(16) unsigned char  VtB[64 * 416];
  int bh = blockIdx.x;
  int b = bh / NH, h = bh - b * NH;
  int tid = threadIdx.x, lane = tid & 63, wid = tid >> 6;
  int g = lane >> 4, l = lane & 15;
  const unsigned short* Cb = cqkv + (b * SKV) * NCOL + h * 64;

  if (tid < 64) *(unsigned*)(VtB + vt_off(tid, 206)) = 0u;
  for (int i = tid; i < 208 * 8; i += 256) {
    int row = i >> 3, gg = i & 7;
    int srow = (row < SKV) ? row : (SKV - 1);
    u32x4 v = *(const u32x4*)(Cb + srow * NCOL + 768 + gg * 8);
    *(u32x4*)((unsigned char*)Ksh + ((row * 128 + gg * 16) ^ ((row & 7) << 4))) = v;
  }
  for (int i = tid; i < 206 * 8; i += 256) {
    int key = i >> 3, gg = i & 7;
    u32x4 v = *(const u32x4*)(Cb + key * NCOL + 1536 + gg * 8);
    union { u32x4 v4; unsigned short e[8]; } u; u.v4 = v;
#pragma unroll
    for (int j = 0; j < 8; ++j)
      *(unsigned short*)(VtB + vt_off(gg * 8 + j, key)) = u.e[j];
  }
  __syncthreads();

  const float scale = 0.125f;
  f32x4 zero4 = {0.f, 0.f, 0.f, 0.f};
  int srcA = ((g & 1) << 5) + l;
  int srcB = srcA + 16;
  bool hiHalf = (g >= 2);

  for (int qt = wid; qt < 13; qt += 4) {
    int qr = qt * 16 + l;
    int qld = qr > 197 ? 197 : qr;
    const unsigned short* qp = Cb + qld * NCOL + g * 8;
    bf16x8 qa0 = *(const bf16x8*)qp;
    bf16x8 qa1 = *(const bf16x8*)(qp + 32);

    f32x4 sc[13];
#pragma unroll
    for (int nt = 0; nt < 13; ++nt) sc[nt] = zero4;
#pragma unroll
    for (int nt = 0; nt < 13; ++nt) {
      int key = nt * 16 + l;
      int rb = key * 128, sw = (key & 7) << 4, kb = g * 16;
      bf16x8 kb0 = *(const bf16x8*)((const unsigned char*)Ksh + rb + (kb ^ sw));
      bf16x8 kb1 = *(const bf16x8*)((const unsigned char*)Ksh + rb + ((kb + 64) ^ sw));
      sc[nt] = __builtin_amdgcn_mfma_f32_16x16x32_bf16(kb0, qa0, sc[nt], 0, 0, 0);
      sc[nt] = __builtin_amdgcn_mfma_f32_16x16x32_bf16(kb1, qa1, sc[nt], 0, 0, 0);
    }

    float mx = -1e30f;
#pragma unroll
    for (int nt = 0; nt < 13; ++nt)
#pragma unroll
      for (int r = 0; r < 4; ++r) {
        int key = nt * 16 + g * 4 + r;
        float s = sc[nt][r] * scale;
        bool ok = (key < 197 || qr == 197) && (key < SKV);
        s = ok ? s : -1e30f;
        sc[nt][r] = s;
        mx = fmaxf(mx, s);
      }
    mx = fmaxf(mx, __shfl_xor(mx, 16));
    mx = fmaxf(mx, __shfl_xor(mx, 32));
    float sum = 0.f;
#pragma unroll
    for (int nt = 0; nt < 13; ++nt)
#pragma unroll
      for (int r = 0; r < 4; ++r) {
        float p = __expf(sc[nt][r] - mx);
        sc[nt][r] = p;
        sum += p;
      }
    sum += __shfl_xor(sum, 16);
    sum += __shfl_xor(sum, 32);
    float inv = 1.0f / sum;

    unsigned pk0[13], pk1[13];
#pragma unroll
    for (int nt = 0; nt < 13; ++nt) {
      asm("v_cvt_pk_bf16_f32 %0, %1, %2" : "=v"(pk0[nt]) : "v"(sc[nt][0]), "v"(sc[nt][1]));
      asm("v_cvt_pk_bf16_f32 %0, %1, %2" : "=v"(pk1[nt]) : "v"(sc[nt][2]), "v"(sc[nt][3]));
    }

    f32x4 ctx[4];
#pragma unroll
    for (int dt = 0; dt < 4; ++dt) ctx[dt] = zero4;
#pragma unroll
    for (int c = 0; c < 7; ++c) {
      union { unsigned w[4]; bf16x8 v; } pa;
      if (c < 6) {
        int n0 = 2 * c, n1 = 2 * c + 1;
        unsigned a0 = (unsigned)__shfl((int)pk0[n0], srcA), b0 = (unsigned)__shfl((int)pk0[n1], srcA);
        unsigned a1 = (unsigned)__shfl((int)pk1[n0], srcA), b1 = (unsigned)__shfl((int)pk1[n1], srcA);
        unsigned a2 = (unsigned)__shfl((int)pk0[n0], srcB), b2 = (unsigned)__shfl((int)pk0[n1], srcB);
        unsigned a3 = (unsigned)__shfl((int)pk1[n0], srcB), b3 = (unsigned)__shfl((int)pk1[n1], srcB);
        pa.w[0] = hiHalf ? b0 : a0;
        pa.w[1] = hiHalf ? b1 : a1;
        pa.w[2] = hiHalf ? b2 : a2;
        pa.w[3] = hiHalf ? b3 : a3;
      } else {
        unsigned a0 = (unsigned)__shfl((int)pk0[12], srcA);
        unsigned a1 = (unsigned)__shfl((int)pk1[12], srcA);
        unsigned a2 = (unsigned)__shfl((int)pk0[12], srcB);
        unsigned a3 = (unsigned)__shfl((int)pk1[12], srcB);
        pa.w[0] = hiHalf ? 0u : a0;
        pa.w[1] = hiHalf ? 0u : a1;
        pa.w[2] = hiHalf ? 0u : a2;
        pa.w[3] = hiHalf ? 0u : a3;
      }
      int colb = c * 32 + g * 8;
      if (c == 6 && hiHalf) colb = 0;
#pragma unroll
      for (int dt = 0; dt < 4; ++dt) {
        bf16x8 vb = *(const bf16x8*)(VtB + vt_off(dt * 16 + l, colb));
        ctx[dt] = __builtin_amdgcn_mfma_f32_16x16x32_bf16(pa.v, vb, ctx[dt], 0, 0, 0);
      }
    }

    float invr[4];
#pragma unroll
    for (int r = 0; r < 4; ++r) invr[r] = __shfl(inv, g * 4 + r);
#pragma unroll
    for (int dt = 0; dt < 4; ++dt)
#pragma unroll
      for (int r = 0; r < 4; ++r) {
        int qo = qt * 16 + g * 4 + r;
        if (qo < SQ)
          out[(b * SQ + qo) * DM + h * 64 + dt * 16 + l] = ctx[dt][r] * invr[r];
      }
  }
}

extern "C" void kernel_launch(void* const* d_in, const int* in_sizes, int n_in,
                              void* d_out, int out_size, void* d_ws, size_t ws_size,
                              hipStream_t stream) {
  const float* hid = (const float*)d_in[0];
  const float* mem = (const float*)d_in[1];
  const float* Wq  = (const float*)d_in[2];
  const float* bq  = (const float*)d_in[3];
  const float* Wk  = (const float*)d_in[4];
  const float* bk  = (const float*)d_in[5];
  const float* Wv  = (const float*)d_in[6];
  const float* bv  = (const float*)d_in[7];
  float* out = (float*)d_out;

  unsigned short* xkv  = (unsigned short*)d_ws;
  unsigned short* wt   = xkv + NROWS * DM;
  unsigned short* cbuf = wt + 3 * DM * DM;

  k_conv<<<dim3(NCONVX + 432), 256, 0, stream>>>(hid, mem, Wq, Wk, Wv, xkv, wt);
  k_gemm<<<dim3(927), 512, 0, stream>>>(xkv, wt, bq, bk, bv, cbuf);
  k_attn<<<dim3(NB * NH), 256, 0, stream>>>(cbuf, out);
}